// Round 3
// baseline (384.337 us; speedup 1.0000x reference)
//
#include <hip/hip_runtime.h>
#include <math.h>

typedef unsigned short u16;
typedef __attribute__((ext_vector_type(4))) float f32x4;
typedef __attribute__((ext_vector_type(16))) float f32x16;
typedef __attribute__((ext_vector_type(4))) unsigned short u16x4;
typedef __attribute__((ext_vector_type(8))) __bf16 bf16x8;

static constexpr int SS   = 2048;   // seq len
static constexpr int DD   = 1024;   // model dim
static constexpr int HH   = 16;     // heads
static constexpr int DH   = 64;     // head dim
static constexpr int NTOK = 4096;   // B*S
static constexpr int NQKV = 3072;

#define DEV static __device__ __forceinline__
#define GLD_AS1(p) ((__attribute__((address_space(1))) void*)(void*)(p))
#define GLD_AS3(p) ((__attribute__((address_space(3))) void*)(p))

DEV u16 f2bf(float f) {
    union { float f; unsigned int i; } v; v.f = f;
    unsigned int r = v.i + 0x7fffu + ((v.i >> 16) & 1u);
    return (u16)(r >> 16);
}

DEV f32x4 MFMA(bf16x8 a, bf16x8 b, f32x4 c) {
    return __builtin_amdgcn_mfma_f32_16x16x32_bf16(a, b, c, 0, 0, 0);
}
DEV f32x16 MFMA32(bf16x8 a, bf16x8 b, f32x16 c) {
    return __builtin_amdgcn_mfma_f32_32x32x16_bf16(a, b, c, 0, 0, 0);
}
DEV f32x16 zero16() {
    f32x16 z;
    #pragma unroll
    for (int i = 0; i < 16; i++) z[i] = 0.f;
    return z;
}

// ---------------- transpose fp32 [R][C] -> bf16 [C][R] ----------------
__global__ __launch_bounds__(256)
void k_transpose(const float* __restrict__ in, u16* __restrict__ out, int R, int C) {
    __shared__ float tile[32][33];
    int c0 = blockIdx.x * 32, r0 = blockIdx.y * 32;
    int tx = threadIdx.x, ty = threadIdx.y; // 32 x 8
    #pragma unroll
    for (int i = 0; i < 32; i += 8)
        tile[ty + i][tx] = in[(size_t)(r0 + ty + i) * C + c0 + tx];
    __syncthreads();
    #pragma unroll
    for (int i = 0; i < 32; i += 8)
        out[(size_t)(c0 + ty + i) * R + r0 + tx] = f2bf(tile[tx][ty + i]);
}

// ---------------- layernorm fp32 -> bf16, one block per row ----------------
__global__ __launch_bounds__(256)
void k_layernorm(const float* __restrict__ x, const float* __restrict__ g,
                 const float* __restrict__ b, u16* __restrict__ out) {
    int row = blockIdx.x, t = threadIdx.x;
    const float4* xp = reinterpret_cast<const float4*>(x + (size_t)row * DD);
    float4 v = xp[t];
    float s = v.x + v.y + v.z + v.w;
    float q = v.x * v.x + v.y * v.y + v.z * v.z + v.w * v.w;
    #pragma unroll
    for (int m = 1; m < 64; m <<= 1) { s += __shfl_xor(s, m); q += __shfl_xor(q, m); }
    __shared__ float ps[4], pq[4];
    int w = t >> 6, l = t & 63;
    if (l == 0) { ps[w] = s; pq[w] = q; }
    __syncthreads();
    s = ps[0] + ps[1] + ps[2] + ps[3];
    q = pq[0] + pq[1] + pq[2] + pq[3];
    float mu = s * (1.0f / DD);
    float var = q * (1.0f / DD) - mu * mu;
    float rstd = rsqrtf(var + 1e-5f);
    float4 gv = reinterpret_cast<const float4*>(g)[t];
    float4 bv = reinterpret_cast<const float4*>(b)[t];
    u16x4 o;
    o.x = f2bf((v.x - mu) * rstd * gv.x + bv.x);
    o.y = f2bf((v.y - mu) * rstd * gv.y + bv.y);
    o.z = f2bf((v.z - mu) * rstd * gv.z + bv.z);
    o.w = f2bf((v.w - mu) * rstd * gv.w + bv.w);
    reinterpret_cast<u16x4*>(out + (size_t)row * DD)[t] = o;
}

// ---------------- GEMM: C[M,N] = A[M,K](bf16) @ BT[N,K](bf16)^T ----------------
// Staging via global_load_lds (16B) with pre-swizzled global source:
// LDS slot (row r, in-row byte x) holds global (r, x ^ ((r&7)<<4));
// lane l of chunk c: r = c*8 + (l>>3), fetches global col bytes ((l&7)^(l>>3))<<4.
// MODE 0: qkv split -> Cb (cols<2048), vT[b][h][d][s] (cols>=2048)
// MODE 1: Cf = acc + bias[n] + res[m*N+n]   (fp32 out)
// MODE 2: Cb = bf16( gelu(acc + bias[n]) )
template<int MODE>
__global__ __launch_bounds__(256)
void k_gemm(const u16* __restrict__ A, const u16* __restrict__ BT,
            float* __restrict__ Cf, u16* __restrict__ Cb,
            const float* __restrict__ bias, const float* __restrict__ res,
            u16* __restrict__ vT, int M, int N, int K) {
    __shared__ __align__(128) char lds[32768];
    char* Al = lds;
    char* Bl = lds + 16384;
    const int t = threadIdx.x;
    const int w = t >> 6, l = t & 63;
    const int lg = l >> 4, lr = l & 15;
    const int m0 = blockIdx.y * 128, n0 = blockIdx.x * 128;
    const int wr = w >> 1, wc = w & 1;

    // per-lane source offset (elements) within a 64-col K-slab, pre-swizzled
    const int csw = ((l & 7) ^ (l >> 3)) << 3;

    f32x4 acc[4][4];
    #pragma unroll
    for (int i = 0; i < 4; i++)
        #pragma unroll
        for (int j = 0; j < 4; j++)
            acc[i][j] = (f32x4){0.f, 0.f, 0.f, 0.f};

    for (int kt = 0; kt < K; kt += 64) {
        __syncthreads();
        #pragma unroll
        for (int i = 0; i < 4; i++) {
            const int chunk = w * 4 + i;          // 0..15
            const int r = chunk * 8 + (l >> 3);   // tile row 0..127
            const u16* ga = A  + (size_t)(m0 + r) * K + kt + csw;
            const u16* gb = BT + (size_t)(n0 + r) * K + kt + csw;
            __builtin_amdgcn_global_load_lds(GLD_AS1(ga), GLD_AS3(Al + chunk * 1024), 16, 0, 0);
            __builtin_amdgcn_global_load_lds(GLD_AS1(gb), GLD_AS3(Bl + chunk * 1024), 16, 0, 0);
        }
        __syncthreads();
        #pragma unroll
        for (int s = 0; s < 2; s++) {
            const int swz = (s * 64 + lg * 16) ^ ((lr & 7) << 4);
            bf16x8 af[4], bfr[4];
            #pragma unroll
            for (int mi = 0; mi < 4; mi++)
                af[mi] = *reinterpret_cast<const bf16x8*>(Al + (wr * 64 + mi * 16 + lr) * 128 + swz);
            #pragma unroll
            for (int ni = 0; ni < 4; ni++)
                bfr[ni] = *reinterpret_cast<const bf16x8*>(Bl + (wc * 64 + ni * 16 + lr) * 128 + swz);
            #pragma unroll
            for (int mi = 0; mi < 4; mi++)
                #pragma unroll
                for (int ni = 0; ni < 4; ni++)
                    acc[mi][ni] = MFMA(af[mi], bfr[ni], acc[mi][ni]);
        }
    }

    // epilogue
    #pragma unroll
    for (int mi = 0; mi < 4; mi++) {
        #pragma unroll
        for (int ni = 0; ni < 4; ni++) {
            int nn = n0 + wc * 64 + ni * 16 + lr;
            #pragma unroll
            for (int r = 0; r < 4; r++) {
                int mm = m0 + wr * 64 + mi * 16 + lg * 4 + r;
                float v = acc[mi][ni][r];
                if (MODE == 0) {
                    if (nn < 2048) {
                        Cb[(size_t)mm * NQKV + nn] = f2bf(v);
                    } else {
                        int b = mm >> 11, sIdx = mm & 2047;
                        int hd = nn - 2048;
                        vT[(((size_t)(b * HH + (hd >> 6)) * DH) + (hd & 63)) * SS + sIdx] = f2bf(v);
                    }
                } else if (MODE == 1) {
                    Cf[(size_t)mm * N + nn] = v + bias[nn] + res[(size_t)mm * N + nn];
                } else {
                    float u = v + bias[nn];
                    float gl = 0.5f * u * (1.0f + erff(u * 0.70710678118654752f));
                    Cb[(size_t)mm * N + nn] = f2bf(gl);
                }
            }
        }
    }
}

// ---------------- flash attention, swapped-QK 32x32, KV-split x2 ----------------
// Wave pair (2t, 2t+1) handles q-tile t; each wave does half the kv range (1024),
// then the pair merges (m,l,O) through LDS. 4096 waves -> ~4/SIMD occupancy.
__global__ __launch_bounds__(256)
void k_attn(const u16* __restrict__ qkv, const u16* __restrict__ vT,
            u16* __restrict__ out) {
    const int w = threadIdx.x >> 6, l = threadIdx.x & 63;
    const int q = l & 31, hi = l >> 5;
    const int task = blockIdx.x * 2 + (w >> 1);  // 0..2047
    const int half = w & 1;
    const int pair = w >> 1;
    const int bh = task >> 6;                    // 0..31
    const int q32 = task & 63;
    const int b = bh >> 4, h = bh & 15;
    const size_t rowbase = (size_t)b * SS;
    const int q0 = q32 * 32;

    __shared__ float ml[4][32][2];
    __shared__ __align__(16) f32x4 obuf[2][64][8];

    // Q B-fragments: B[k=dk][n=q]: lane needs Q[q0+q][h*64 + ks*16 + hi*8 + j]
    const u16* qrow = qkv + (rowbase + q0 + q) * NQKV + h * DH + hi * 8;
    bf16x8 qf[4];
    #pragma unroll
    for (int ks = 0; ks < 4; ks++)
        qf[ks] = *reinterpret_cast<const bf16x8*>(qrow + ks * 16);

    f32x16 o0 = zero16(), o1 = zero16();     // O^T[d][q], d-tiles 0/1
    float mQ = -1e30f, lQ = 0.f;

    const u16* kbase = qkv + rowbase * NQKV + 1024 + h * DH;
    const u16* vbase = vT + (size_t)bh * DH * SS;

    const int kvBeg = half * 1024, kvEnd = kvBeg + 1024;
    for (int kv0 = kvBeg; kv0 < kvEnd; kv0 += 32) {
        // K A-fragments: A[m=kv][k=dk]: row kv0+(l&31), cols ks*16+hi*8
        const u16* kp = kbase + (size_t)(kv0 + q) * NQKV + hi * 8;
        f32x16 st = zero16();
        st = MFMA32(*reinterpret_cast<const bf16x8*>(kp),      qf[0], st);
        st = MFMA32(*reinterpret_cast<const bf16x8*>(kp + 16), qf[1], st);
        st = MFMA32(*reinterpret_cast<const bf16x8*>(kp + 32), qf[2], st);
        st = MFMA32(*reinterpret_cast<const bf16x8*>(kp + 48), qf[3], st);

        f32x16 sc = st * 0.125f;
        float tm = sc[0];
        #pragma unroll
        for (int i = 1; i < 16; i++) tm = fmaxf(tm, sc[i]);
        tm = fmaxf(tm, __shfl_xor(tm, 32));

        // defer-max (T13): rescale only when max grew by > 8
        if (!__all(tm - mQ <= 8.f)) {
            float mn = fmaxf(mQ, tm);
            float scale = __expf(mQ - mn);
            lQ *= scale;
            o0 *= scale;
            o1 *= scale;
            mQ = mn;
        }

        f32x16 p;
        #pragma unroll
        for (int i = 0; i < 16; i++) p[i] = __expf(sc[i] - mQ);
        float ts = p[0];
        #pragma unroll
        for (int i = 1; i < 16; i++) ts += p[i];
        ts += __shfl_xor(ts, 32);
        lQ += ts;

        // pack P to bf16 words
        union W { unsigned int u; __bf16 h[2]; };
        W pw[8];
        #pragma unroll
        for (int m = 0; m < 8; m++) {
            pw[m].h[0] = (__bf16)p[2 * m];
            pw[m].h[1] = (__bf16)p[2 * m + 1];
        }

        // build P B-fragments B[k=kv][n=q] for kk=0,1 (kv slices of 16)
        bf16x8 pf[2];
        #pragma unroll
        for (int kk = 0; kk < 2; kk++) {
            unsigned int a0 = pw[4 * kk + 0].u, a1 = pw[4 * kk + 1].u;
            unsigned int b0 = pw[4 * kk + 2].u, b1 = pw[4 * kk + 3].u;
            unsigned int own0 = hi ? b0 : a0, own1 = hi ? b1 : a1;
            unsigned int snd0 = hi ? a0 : b0, snd1 = hi ? a1 : b1;
            unsigned int r0 = __shfl_xor(snd0, 32), r1 = __shfl_xor(snd1, 32);
            union F { unsigned int u[4]; bf16x8 v; } f;
            f.u[0] = hi ? r0 : own0;
            f.u[1] = hi ? r1 : own1;
            f.u[2] = hi ? own0 : r0;
            f.u[3] = hi ? own1 : r1;
            pf[kk] = f.v;
        }

        // PV: A=V^T[d][kv] from vT (contiguous 16B), accumulate O^T
        #pragma unroll
        for (int kk = 0; kk < 2; kk++) {
            const u16* vp = vbase + (size_t)q * SS + kv0 + kk * 16 + hi * 8;
            o0 = MFMA32(*reinterpret_cast<const bf16x8*>(vp), pf[kk], o0);
            o1 = MFMA32(*reinterpret_cast<const bf16x8*>(vp + 32 * SS), pf[kk], o1);
        }
    }

    // ---- pair merge ----
    if (hi == 0) { ml[w][q][0] = mQ; ml[w][q][1] = lQ; }
    __syncthreads();
    const int pw2 = w ^ 1;
    const float mO = ml[pw2][q][0];
    const float lO = ml[pw2][q][1];
    const float mT = fmaxf(mQ, mO);
    const float myS = __expf(mQ - mT);
    lQ *= myS;
    o0 *= myS;
    o1 *= myS;
    if (half) {
        union U { f32x16 v; f32x4 s[4]; } u0, u1;
        u0.v = o0; u1.v = o1;
        #pragma unroll
        for (int j = 0; j < 4; j++) obuf[pair][l][j ^ (l & 7)] = u0.s[j];
        #pragma unroll
        for (int j = 0; j < 4; j++) obuf[pair][l][(4 + j) ^ (l & 7)] = u1.s[j];
    }
    __syncthreads();
    if (!half) {
        const float lT = lQ + lO * __expf(mO - mT);
        const float invl = 1.0f / lT;
        union U { f32x16 v; f32x4 s[4]; } u0, u1;
        #pragma unroll
        for (int j = 0; j < 4; j++) u0.s[j] = obuf[pair][l][j ^ (l & 7)];
        #pragma unroll
        for (int j = 0; j < 4; j++) u1.s[j] = obuf[pair][l][(4 + j) ^ (l & 7)];
        o0 += u0.v;
        o1 += u1.v;
        // epilogue: lane q; reg r -> d = dt*32 + (r&3) + 8*(r>>2) + 4*hi
        u16* orow = out + (rowbase + q0 + q) * DD + h * DH + hi * 4;
        #pragma unroll
        for (int a = 0; a < 4; a++) {
            u16x4 s0v, s1v;
            #pragma unroll
            for (int i = 0; i < 4; i++) {
                s0v[i] = f2bf(o0[4 * a + i] * invl);
                s1v[i] = f2bf(o1[4 * a + i] * invl);
            }
            *reinterpret_cast<u16x4*>(orow + 8 * a)      = s0v;
            *reinterpret_cast<u16x4*>(orow + 32 + 8 * a) = s1v;
        }
    }
}

extern "C" void kernel_launch(void* const* d_in, const int* in_sizes, int n_in,
                              void* d_out, int out_size, void* d_ws, size_t ws_size,
                              hipStream_t stream) {
    (void)in_sizes; (void)n_in; (void)out_size; (void)ws_size;
    const float* x     = (const float*)d_in[0];
    const float* w_qkv = (const float*)d_in[1];
    const float* w_out = (const float*)d_in[2];
    const float* b_out = (const float*)d_in[3];
    const float* g1    = (const float*)d_in[4];
    const float* be1   = (const float*)d_in[5];
    const float* g2    = (const float*)d_in[6];
    const float* be2   = (const float*)d_in[7];
    const float* w_ff1 = (const float*)d_in[8];
    const float* b_ff1 = (const float*)d_in[9];
    const float* w_ff2 = (const float*)d_in[10];
    const float* b_ff2 = (const float*)d_in[11];

    char* ws = (char*)d_ws;
    u16*   W  = (u16*)(ws);                  //  8.39 MB  (weight^T scratch, reused)
    u16*   Hb = (u16*)(ws + 8388608);        //  8.39 MB  (LN output bf16)
    u16*   QF = (u16*)(ws + 16777216);       // 33.55 MB  (qkv, later ffn act)
    u16*   VT = (u16*)(ws + 50331648);       //  8.39 MB  (v transposed)
    u16*   AO = (u16*)(ws + 58720256);       //  8.39 MB  (attn out bf16)
    float* X1 = (float*)(ws + 67108864);     // 16.78 MB  (post-attn residual fp32)
    float* OUT = (float*)d_out;

    // LN1: x -> Hb
    k_layernorm<<<NTOK, 256, 0, stream>>>(x, g1, be1, Hb);
    // w_qkv^T
    k_transpose<<<dim3(3072 / 32, 1024 / 32), dim3(32, 8), 0, stream>>>(w_qkv, W, 1024, 3072);
    // qkv = Hb @ w_qkv   (v written transposed to VT)
    k_gemm<0><<<dim3(3072 / 128, 4096 / 128), 256, 0, stream>>>(
        Hb, W, nullptr, QF, nullptr, nullptr, VT, NTOK, NQKV, 1024);
    // attention (4096 waves, kv-split pairs)
    k_attn<<<1024, 256, 0, stream>>>(QF, VT, AO);
    // w_out^T
    k_transpose<<<dim3(1024 / 32, 1024 / 32), dim3(32, 8), 0, stream>>>(w_out, W, 1024, 1024);
    // X1 = x + AO @ w_out + b_out
    k_gemm<1><<<dim3(1024 / 128, 4096 / 128), 256, 0, stream>>>(
        AO, W, X1, nullptr, b_out, x, nullptr, NTOK, 1024, 1024);
    // LN2: X1 -> Hb
    k_layernorm<<<NTOK, 256, 0, stream>>>(X1, g2, be2, Hb);
    // w_ff1^T
    k_transpose<<<dim3(4096 / 32, 1024 / 32), dim3(32, 8), 0, stream>>>(w_ff1, W, 1024, 4096);
    // FFA = gelu(Hb @ w_ff1 + b_ff1)  (into QF region)
    k_gemm<2><<<dim3(4096 / 128, 4096 / 128), 256, 0, stream>>>(
        Hb, W, nullptr, QF, b_ff1, nullptr, nullptr, NTOK, 4096, 1024);
    // w_ff2^T
    k_transpose<<<dim3(1024 / 32, 4096 / 32), dim3(32, 8), 0, stream>>>(w_ff2, W, 4096, 1024);
    // OUT = X1 + FFA @ w_ff2 + b_ff2
    k_gemm<1><<<dim3(1024 / 128, 4096 / 128), 256, 0, stream>>>(
        QF, W, OUT, nullptr, b_ff2, X1, nullptr, NTOK, 1024, 4096);
}

// Round 4
// 321.283 us; speedup vs baseline: 1.1963x; 1.1963x over previous
//
#include <hip/hip_runtime.h>
#include <math.h>

typedef unsigned short u16;
typedef __attribute__((ext_vector_type(4))) float f32x4;
typedef __attribute__((ext_vector_type(16))) float f32x16;
typedef __attribute__((ext_vector_type(4))) unsigned short u16x4;
typedef __attribute__((ext_vector_type(8))) __bf16 bf16x8;

static constexpr int SS   = 2048;   // seq len
static constexpr int DD   = 1024;   // model dim
static constexpr int HH   = 16;     // heads
static constexpr int DH   = 64;     // head dim
static constexpr int NTOK = 4096;   // B*S
static constexpr int NQKV = 3072;

#define DEV static __device__ __forceinline__
#define GLD_AS1(p) ((__attribute__((address_space(1))) void*)(void*)(p))
#define GLD_AS3(p) ((__attribute__((address_space(3))) void*)(p))

DEV u16 f2bf(float f) {
    union { float f; unsigned int i; } v; v.f = f;
    unsigned int r = v.i + 0x7fffu + ((v.i >> 16) & 1u);
    return (u16)(r >> 16);
}

DEV f32x4 MFMA(bf16x8 a, bf16x8 b, f32x4 c) {
    return __builtin_amdgcn_mfma_f32_16x16x32_bf16(a, b, c, 0, 0, 0);
}
DEV f32x16 MFMA32(bf16x8 a, bf16x8 b, f32x16 c) {
    return __builtin_amdgcn_mfma_f32_32x32x16_bf16(a, b, c, 0, 0, 0);
}
DEV f32x16 zero16() {
    f32x16 z;
    #pragma unroll
    for (int i = 0; i < 16; i++) z[i] = 0.f;
    return z;
}

// ---------------- transpose fp32 [R][C] -> bf16 [C][R] ----------------
__global__ __launch_bounds__(256)
void k_transpose(const float* __restrict__ in, u16* __restrict__ out, int R, int C) {
    __shared__ float tile[32][33];
    int c0 = blockIdx.x * 32, r0 = blockIdx.y * 32;
    int tx = threadIdx.x, ty = threadIdx.y; // 32 x 8
    #pragma unroll
    for (int i = 0; i < 32; i += 8)
        tile[ty + i][tx] = in[(size_t)(r0 + ty + i) * C + c0 + tx];
    __syncthreads();
    #pragma unroll
    for (int i = 0; i < 32; i += 8)
        out[(size_t)(c0 + ty + i) * R + r0 + tx] = f2bf(tile[tx][ty + i]);
}

// ---------------- layernorm fp32 -> bf16, one block per row ----------------
__global__ __launch_bounds__(256)
void k_layernorm(const float* __restrict__ x, const float* __restrict__ g,
                 const float* __restrict__ b, u16* __restrict__ out) {
    int row = blockIdx.x, t = threadIdx.x;
    const float4* xp = reinterpret_cast<const float4*>(x + (size_t)row * DD);
    float4 v = xp[t];
    float s = v.x + v.y + v.z + v.w;
    float q = v.x * v.x + v.y * v.y + v.z * v.z + v.w * v.w;
    #pragma unroll
    for (int m = 1; m < 64; m <<= 1) { s += __shfl_xor(s, m); q += __shfl_xor(q, m); }
    __shared__ float ps[4], pq[4];
    int w = t >> 6, l = t & 63;
    if (l == 0) { ps[w] = s; pq[w] = q; }
    __syncthreads();
    s = ps[0] + ps[1] + ps[2] + ps[3];
    q = pq[0] + pq[1] + pq[2] + pq[3];
    float mu = s * (1.0f / DD);
    float var = q * (1.0f / DD) - mu * mu;
    float rstd = rsqrtf(var + 1e-5f);
    float4 gv = reinterpret_cast<const float4*>(g)[t];
    float4 bv = reinterpret_cast<const float4*>(b)[t];
    u16x4 o;
    o.x = f2bf((v.x - mu) * rstd * gv.x + bv.x);
    o.y = f2bf((v.y - mu) * rstd * gv.y + bv.y);
    o.z = f2bf((v.z - mu) * rstd * gv.z + bv.z);
    o.w = f2bf((v.w - mu) * rstd * gv.w + bv.w);
    reinterpret_cast<u16x4*>(out + (size_t)row * DD)[t] = o;
}

// ---------------- GEMM: C[M,N] = A[M,K](bf16) @ BT[N,K](bf16)^T ----------------
// Staging via global_load_lds (16B) with pre-swizzled global source.
template<int MODE>
__global__ __launch_bounds__(256)
void k_gemm(const u16* __restrict__ A, const u16* __restrict__ BT,
            float* __restrict__ Cf, u16* __restrict__ Cb,
            const float* __restrict__ bias, const float* __restrict__ res,
            u16* __restrict__ vT, int M, int N, int K) {
    __shared__ __align__(128) char lds[32768];
    char* Al = lds;
    char* Bl = lds + 16384;
    const int t = threadIdx.x;
    const int w = t >> 6, l = t & 63;
    const int lg = l >> 4, lr = l & 15;
    const int m0 = blockIdx.y * 128, n0 = blockIdx.x * 128;
    const int wr = w >> 1, wc = w & 1;

    const int csw = ((l & 7) ^ (l >> 3)) << 3;

    f32x4 acc[4][4];
    #pragma unroll
    for (int i = 0; i < 4; i++)
        #pragma unroll
        for (int j = 0; j < 4; j++)
            acc[i][j] = (f32x4){0.f, 0.f, 0.f, 0.f};

    for (int kt = 0; kt < K; kt += 64) {
        __syncthreads();
        #pragma unroll
        for (int i = 0; i < 4; i++) {
            const int chunk = w * 4 + i;          // 0..15
            const int r = chunk * 8 + (l >> 3);   // tile row 0..127
            const u16* ga = A  + (size_t)(m0 + r) * K + kt + csw;
            const u16* gb = BT + (size_t)(n0 + r) * K + kt + csw;
            __builtin_amdgcn_global_load_lds(GLD_AS1(ga), GLD_AS3(Al + chunk * 1024), 16, 0, 0);
            __builtin_amdgcn_global_load_lds(GLD_AS1(gb), GLD_AS3(Bl + chunk * 1024), 16, 0, 0);
        }
        __syncthreads();
        #pragma unroll
        for (int s = 0; s < 2; s++) {
            const int swz = (s * 64 + lg * 16) ^ ((lr & 7) << 4);
            bf16x8 af[4], bfr[4];
            #pragma unroll
            for (int mi = 0; mi < 4; mi++)
                af[mi] = *reinterpret_cast<const bf16x8*>(Al + (wr * 64 + mi * 16 + lr) * 128 + swz);
            #pragma unroll
            for (int ni = 0; ni < 4; ni++)
                bfr[ni] = *reinterpret_cast<const bf16x8*>(Bl + (wc * 64 + ni * 16 + lr) * 128 + swz);
            #pragma unroll
            for (int mi = 0; mi < 4; mi++)
                #pragma unroll
                for (int ni = 0; ni < 4; ni++)
                    acc[mi][ni] = MFMA(af[mi], bfr[ni], acc[mi][ni]);
        }
    }

    // epilogue
    #pragma unroll
    for (int mi = 0; mi < 4; mi++) {
        #pragma unroll
        for (int ni = 0; ni < 4; ni++) {
            int nn = n0 + wc * 64 + ni * 16 + lr;
            #pragma unroll
            for (int r = 0; r < 4; r++) {
                int mm = m0 + wr * 64 + mi * 16 + lg * 4 + r;
                float v = acc[mi][ni][r];
                if (MODE == 0) {
                    if (nn < 2048) {
                        Cb[(size_t)mm * NQKV + nn] = f2bf(v);
                    } else {
                        int b = mm >> 11, sIdx = mm & 2047;
                        int hd = nn - 2048;
                        vT[(((size_t)(b * HH + (hd >> 6)) * DH) + (hd & 63)) * SS + sIdx] = f2bf(v);
                    }
                } else if (MODE == 1) {
                    Cf[(size_t)mm * N + nn] = v + bias[nn] + res[(size_t)mm * N + nn];
                } else {
                    float u = v + bias[nn];
                    float gl = 0.5f * u * (1.0f + erff(u * 0.70710678118654752f));
                    Cb[(size_t)mm * N + nn] = f2bf(gl);
                }
            }
        }
    }
}

// ---------------- flash attention, swapped-QK 32x32, block-shared K/V in LDS ----
// 4 waves/block = 4 q-tiles of the SAME head; K and V fragment data is identical
// across waves, so each 32-kv tile is staged ONCE per block into LDS via
// global_load_lds (linear dest + pre-swizzled source), double-buffered,
// one barrier per iter. 4x less L1/L2 traffic than per-wave global reads.
// K LDS tile: [32 kv][64 elem], elem ^= ((row&7)<<3)  (GEMM-style XOR swizzle)
// V LDS tile: [32 rows][64 elem]: row r slots 0-3 = V^T row d=r, slots 4-7 = d=r+32.
__global__ __launch_bounds__(256)
void k_attn(const u16* __restrict__ qkv, const u16* __restrict__ vT,
            u16* __restrict__ out) {
    const int w = threadIdx.x >> 6, l = threadIdx.x & 63;
    const int q = l & 31, hi = l >> 5;
    const int bh = blockIdx.x >> 4;          // 0..31
    const int qg = blockIdx.x & 15;
    const int b = bh >> 4, h = bh & 15;
    const size_t rowbase = (size_t)b * SS;
    const int q0 = (qg * 4 + w) * 32;

    __shared__ __align__(128) u16 Kl[2][32 * 64];
    __shared__ __align__(128) u16 Vl[2][32 * 64];

    const u16* kbase = qkv + rowbase * NQKV + 1024 + h * DH;
    const u16* vbase = vT + (size_t)bh * DH * SS;

    // staging: thread -> one 16B chunk of K and one of V per tile.
    // wave w owns LDS chunk w (1024 B = rows w*8..w*8+7); lane l -> row w*8+(l>>3),
    // LDS slot (l&7); source col slot = (l&7)^(l>>3)  (inverse swizzle).
    const int srow = w * 8 + (l >> 3);
    const int sslot = (l & 7) ^ (l >> 3);
    const u16* kg = kbase + (size_t)srow * NQKV + sslot * 8;
    const u16* vg = vbase + (size_t)(srow + 32 * (sslot >> 2)) * SS + (sslot & 3) * 8;

    // Q B-fragments: lane needs Q[q0+q][h*64 + ks*16 + hi*8 + j]
    const u16* qrow = qkv + (rowbase + q0 + q) * NQKV + h * DH + hi * 8;
    bf16x8 qf[4];
    #pragma unroll
    for (int ks = 0; ks < 4; ks++)
        qf[ks] = *reinterpret_cast<const bf16x8*>(qrow + ks * 16);

    f32x16 o0 = zero16(), o1 = zero16();     // O^T[d][q], d-tiles 0/1
    float mQ = -1e30f, lQ = 0.f;

    // prologue: stage tile 0 -> buf 0
    __builtin_amdgcn_global_load_lds(GLD_AS1(kg), GLD_AS3((u16*)Kl[0] + w * 512), 16, 0, 0);
    __builtin_amdgcn_global_load_lds(GLD_AS1(vg), GLD_AS3((u16*)Vl[0] + w * 512), 16, 0, 0);
    __syncthreads();

    int buf = 0;
    for (int kv0 = 0; kv0 < SS; kv0 += 32) {
        if (kv0 + 32 < SS) {
            __builtin_amdgcn_global_load_lds(GLD_AS1(kg + (size_t)(kv0 + 32) * NQKV),
                                             GLD_AS3((u16*)Kl[buf ^ 1] + w * 512), 16, 0, 0);
            __builtin_amdgcn_global_load_lds(GLD_AS1(vg + (kv0 + 32)),
                                             GLD_AS3((u16*)Vl[buf ^ 1] + w * 512), 16, 0, 0);
        }
        const u16* Kb = Kl[buf];
        const u16* Vb = Vl[buf];
        const int qsw = (q & 7) << 3;

        f32x16 st = zero16();
        #pragma unroll
        for (int ks = 0; ks < 4; ks++) {
            bf16x8 kf = *reinterpret_cast<const bf16x8*>(Kb + q * 64 + ((ks * 16 + hi * 8) ^ qsw));
            st = MFMA32(kf, qf[ks], st);
        }

        f32x16 sc = st * 0.125f;
        float tm = sc[0];
        #pragma unroll
        for (int i = 1; i < 16; i++) tm = fmaxf(tm, sc[i]);
        tm = fmaxf(tm, __shfl_xor(tm, 32));

        // defer-max (T13)
        if (!__all(tm - mQ <= 8.f)) {
            float mn = fmaxf(mQ, tm);
            float scale = __expf(mQ - mn);
            lQ *= scale;
            o0 *= scale;
            o1 *= scale;
            mQ = mn;
        }

        f32x16 p;
        #pragma unroll
        for (int i = 0; i < 16; i++) p[i] = __expf(sc[i] - mQ);
        float ts = p[0];
        #pragma unroll
        for (int i = 1; i < 16; i++) ts += p[i];
        ts += __shfl_xor(ts, 32);
        lQ += ts;

        // pack P to bf16 words
        union W { unsigned int u; __bf16 h[2]; };
        W pw[8];
        #pragma unroll
        for (int m = 0; m < 8; m++) {
            pw[m].h[0] = (__bf16)p[2 * m];
            pw[m].h[1] = (__bf16)p[2 * m + 1];
        }

        // build P B-fragments B[k=kv][n=q] for kk=0,1
        bf16x8 pf[2];
        #pragma unroll
        for (int kk = 0; kk < 2; kk++) {
            unsigned int a0 = pw[4 * kk + 0].u, a1 = pw[4 * kk + 1].u;
            unsigned int b0 = pw[4 * kk + 2].u, b1 = pw[4 * kk + 3].u;
            unsigned int own0 = hi ? b0 : a0, own1 = hi ? b1 : a1;
            unsigned int snd0 = hi ? a0 : b0, snd1 = hi ? a1 : b1;
            unsigned int r0 = __shfl_xor(snd0, 32), r1 = __shfl_xor(snd1, 32);
            union F { unsigned int u[4]; bf16x8 v; } f;
            f.u[0] = hi ? r0 : own0;
            f.u[1] = hi ? r1 : own1;
            f.u[2] = hi ? own0 : r0;
            f.u[3] = hi ? own1 : r1;
            pf[kk] = f.v;
        }

        // PV from LDS V tile: o0 rows d=q (slots 0-3), o1 rows d=q+32 (slots 4-7)
        #pragma unroll
        for (int kk = 0; kk < 2; kk++) {
            bf16x8 v0 = *reinterpret_cast<const bf16x8*>(Vb + q * 64 + ((kk * 16 + hi * 8) ^ qsw));
            bf16x8 v1 = *reinterpret_cast<const bf16x8*>(Vb + q * 64 + ((32 + kk * 16 + hi * 8) ^ qsw));
            o0 = MFMA32(v0, pf[kk], o0);
            o1 = MFMA32(v1, pf[kk], o1);
        }

        __syncthreads();
        buf ^= 1;
    }

    // epilogue: lane q; reg r -> d = dt*32 + (r&3) + 8*(r>>2) + 4*hi
    float invl = 1.0f / lQ;
    u16* orow = out + (rowbase + q0 + q) * DD + h * DH + hi * 4;
    #pragma unroll
    for (int a = 0; a < 4; a++) {
        u16x4 s0v, s1v;
        #pragma unroll
        for (int i = 0; i < 4; i++) {
            s0v[i] = f2bf(o0[4 * a + i] * invl);
            s1v[i] = f2bf(o1[4 * a + i] * invl);
        }
        *reinterpret_cast<u16x4*>(orow + 8 * a)      = s0v;
        *reinterpret_cast<u16x4*>(orow + 32 + 8 * a) = s1v;
    }
}

extern "C" void kernel_launch(void* const* d_in, const int* in_sizes, int n_in,
                              void* d_out, int out_size, void* d_ws, size_t ws_size,
                              hipStream_t stream) {
    (void)in_sizes; (void)n_in; (void)out_size; (void)ws_size;
    const float* x     = (const float*)d_in[0];
    const float* w_qkv = (const float*)d_in[1];
    const float* w_out = (const float*)d_in[2];
    const float* b_out = (const float*)d_in[3];
    const float* g1    = (const float*)d_in[4];
    const float* be1   = (const float*)d_in[5];
    const float* g2    = (const float*)d_in[6];
    const float* be2   = (const float*)d_in[7];
    const float* w_ff1 = (const float*)d_in[8];
    const float* b_ff1 = (const float*)d_in[9];
    const float* w_ff2 = (const float*)d_in[10];
    const float* b_ff2 = (const float*)d_in[11];

    char* ws = (char*)d_ws;
    u16*   W  = (u16*)(ws);                  //  8.39 MB  (weight^T scratch, reused)
    u16*   Hb = (u16*)(ws + 8388608);        //  8.39 MB  (LN output bf16)
    u16*   QF = (u16*)(ws + 16777216);       // 33.55 MB  (qkv, later ffn act)
    u16*   VT = (u16*)(ws + 50331648);       //  8.39 MB  (v transposed)
    u16*   AO = (u16*)(ws + 58720256);       //  8.39 MB  (attn out bf16)
    float* X1 = (float*)(ws + 67108864);     // 16.78 MB  (post-attn residual fp32)
    float* OUT = (float*)d_out;

    // LN1: x -> Hb
    k_layernorm<<<NTOK, 256, 0, stream>>>(x, g1, be1, Hb);
    // w_qkv^T
    k_transpose<<<dim3(3072 / 32, 1024 / 32), dim3(32, 8), 0, stream>>>(w_qkv, W, 1024, 3072);
    // qkv = Hb @ w_qkv   (v written transposed to VT)
    k_gemm<0><<<dim3(3072 / 128, 4096 / 128), 256, 0, stream>>>(
        Hb, W, nullptr, QF, nullptr, nullptr, VT, NTOK, NQKV, 1024);
    // attention (512 blocks, 4 q-tile waves sharing LDS-staged K/V)
    k_attn<<<512, 256, 0, stream>>>(QF, VT, AO);
    // w_out^T
    k_transpose<<<dim3(1024 / 32, 1024 / 32), dim3(32, 8), 0, stream>>>(w_out, W, 1024, 1024);
    // X1 = x + AO @ w_out + b_out
    k_gemm<1><<<dim3(1024 / 128, 4096 / 128), 256, 0, stream>>>(
        AO, W, X1, nullptr, b_out, x, nullptr, NTOK, 1024, 1024);
    // LN2: X1 -> Hb
    k_layernorm<<<NTOK, 256, 0, stream>>>(X1, g2, be2, Hb);
    // w_ff1^T
    k_transpose<<<dim3(4096 / 32, 1024 / 32), dim3(32, 8), 0, stream>>>(w_ff1, W, 1024, 4096);
    // FFA = gelu(Hb @ w_ff1 + b_ff1)  (into QF region)
    k_gemm<2><<<dim3(4096 / 128, 4096 / 128), 256, 0, stream>>>(
        Hb, W, nullptr, QF, b_ff1, nullptr, nullptr, NTOK, 4096, 1024);
    // w_ff2^T
    k_transpose<<<dim3(1024 / 32, 4096 / 32), dim3(32, 8), 0, stream>>>(w_ff2, W, 4096, 1024);
    // OUT = X1 + FFA @ w_ff2 + b_ff2
    k_gemm<1><<<dim3(1024 / 128, 4096 / 128), 256, 0, stream>>>(
        QF, W, OUT, nullptr, b_ff2, X1, nullptr, NTOK, 1024, 4096);
}

// Round 5
// 290.413 us; speedup vs baseline: 1.3234x; 1.1063x over previous
//
#include <hip/hip_runtime.h>
#include <math.h>

typedef unsigned short u16;
typedef __attribute__((ext_vector_type(4))) float f32x4;
typedef __attribute__((ext_vector_type(16))) float f32x16;
typedef __attribute__((ext_vector_type(4))) unsigned short u16x4;
typedef __attribute__((ext_vector_type(8))) __bf16 bf16x8;

static constexpr int SS   = 2048;   // seq len
static constexpr int DD   = 1024;   // model dim
static constexpr int HH   = 16;     // heads
static constexpr int DH   = 64;     // head dim
static constexpr int NTOK = 4096;   // B*S
static constexpr int NQKV = 3072;

#define DEV static __device__ __forceinline__
#define GLD_AS1(p) ((__attribute__((address_space(1))) void*)(void*)(p))
#define GLD_AS3(p) ((__attribute__((address_space(3))) void*)(p))

DEV u16 f2bf(float f) {
    union { float f; unsigned int i; } v; v.f = f;
    unsigned int r = v.i + 0x7fffu + ((v.i >> 16) & 1u);
    return (u16)(r >> 16);
}

DEV f32x4 MFMA(bf16x8 a, bf16x8 b, f32x4 c) {
    return __builtin_amdgcn_mfma_f32_16x16x32_bf16(a, b, c, 0, 0, 0);
}
DEV f32x16 MFMA32(bf16x8 a, bf16x8 b, f32x16 c) {
    return __builtin_amdgcn_mfma_f32_32x32x16_bf16(a, b, c, 0, 0, 0);
}
DEV f32x16 zero16() {
    f32x16 z;
    #pragma unroll
    for (int i = 0; i < 16; i++) z[i] = 0.f;
    return z;
}

// ---------------- transpose fp32 [R][C] -> bf16 [C][R] ----------------
__global__ __launch_bounds__(256)
void k_transpose(const float* __restrict__ in, u16* __restrict__ out, int R, int C) {
    __shared__ float tile[32][33];
    int c0 = blockIdx.x * 32, r0 = blockIdx.y * 32;
    int tx = threadIdx.x, ty = threadIdx.y; // 32 x 8
    #pragma unroll
    for (int i = 0; i < 32; i += 8)
        tile[ty + i][tx] = in[(size_t)(r0 + ty + i) * C + c0 + tx];
    __syncthreads();
    #pragma unroll
    for (int i = 0; i < 32; i += 8)
        out[(size_t)(c0 + ty + i) * R + r0 + tx] = f2bf(tile[tx][ty + i]);
}

// ---------------- layernorm fp32 -> bf16, one block per row ----------------
__global__ __launch_bounds__(256)
void k_layernorm(const float* __restrict__ x, const float* __restrict__ g,
                 const float* __restrict__ b, u16* __restrict__ out) {
    int row = blockIdx.x, t = threadIdx.x;
    const float4* xp = reinterpret_cast<const float4*>(x + (size_t)row * DD);
    float4 v = xp[t];
    float s = v.x + v.y + v.z + v.w;
    float q = v.x * v.x + v.y * v.y + v.z * v.z + v.w * v.w;
    #pragma unroll
    for (int m = 1; m < 64; m <<= 1) { s += __shfl_xor(s, m); q += __shfl_xor(q, m); }
    __shared__ float ps[4], pq[4];
    int w = t >> 6, l = t & 63;
    if (l == 0) { ps[w] = s; pq[w] = q; }
    __syncthreads();
    s = ps[0] + ps[1] + ps[2] + ps[3];
    q = pq[0] + pq[1] + pq[2] + pq[3];
    float mu = s * (1.0f / DD);
    float var = q * (1.0f / DD) - mu * mu;
    float rstd = rsqrtf(var + 1e-5f);
    float4 gv = reinterpret_cast<const float4*>(g)[t];
    float4 bv = reinterpret_cast<const float4*>(b)[t];
    u16x4 o;
    o.x = f2bf((v.x - mu) * rstd * gv.x + bv.x);
    o.y = f2bf((v.y - mu) * rstd * gv.y + bv.y);
    o.z = f2bf((v.z - mu) * rstd * gv.z + bv.z);
    o.w = f2bf((v.w - mu) * rstd * gv.w + bv.w);
    reinterpret_cast<u16x4*>(out + (size_t)row * DD)[t] = o;
}

// ---------------- GEMM: C[M,N] = A[M,K](bf16) @ BT[N,K](bf16)^T ----------------
// 2-phase pipeline: double-buffered LDS (2x32KB); issue global_load_lds for
// k-slab t+1 BEFORE computing slab t; one barrier per iter (drains vmcnt).
template<int MODE>
__global__ __launch_bounds__(256)
void k_gemm(const u16* __restrict__ A, const u16* __restrict__ BT,
            float* __restrict__ Cf, u16* __restrict__ Cb,
            const float* __restrict__ bias, const float* __restrict__ res,
            u16* __restrict__ vT, int M, int N, int K) {
    __shared__ __align__(128) char lds[2][32768];
    const int t = threadIdx.x;
    const int w = t >> 6, l = t & 63;
    const int lg = l >> 4, lr = l & 15;
    const int m0 = blockIdx.y * 128, n0 = blockIdx.x * 128;
    const int wr = w >> 1, wc = w & 1;

    const int csw = ((l & 7) ^ (l >> 3)) << 3;
    const int chunk0 = w * 4;
    const int srow = (l >> 3);

    f32x4 acc[4][4];
    #pragma unroll
    for (int i = 0; i < 4; i++)
        #pragma unroll
        for (int j = 0; j < 4; j++)
            acc[i][j] = (f32x4){0.f, 0.f, 0.f, 0.f};

    // prologue: stage slab 0 into buf 0
    #pragma unroll
    for (int i = 0; i < 4; i++) {
        const int chunk = chunk0 + i;
        const int r = chunk * 8 + srow;
        __builtin_amdgcn_global_load_lds(GLD_AS1(A  + (size_t)(m0 + r) * K + csw),
                                         GLD_AS3(lds[0] + chunk * 1024), 16, 0, 0);
        __builtin_amdgcn_global_load_lds(GLD_AS1(BT + (size_t)(n0 + r) * K + csw),
                                         GLD_AS3(lds[0] + 16384 + chunk * 1024), 16, 0, 0);
    }
    __syncthreads();

    int buf = 0;
    for (int kt = 0; kt < K; kt += 64) {
        if (kt + 64 < K) {
            #pragma unroll
            for (int i = 0; i < 4; i++) {
                const int chunk = chunk0 + i;
                const int r = chunk * 8 + srow;
                __builtin_amdgcn_global_load_lds(GLD_AS1(A  + (size_t)(m0 + r) * K + kt + 64 + csw),
                                                 GLD_AS3(lds[buf ^ 1] + chunk * 1024), 16, 0, 0);
                __builtin_amdgcn_global_load_lds(GLD_AS1(BT + (size_t)(n0 + r) * K + kt + 64 + csw),
                                                 GLD_AS3(lds[buf ^ 1] + 16384 + chunk * 1024), 16, 0, 0);
            }
        }
        const char* Al = lds[buf];
        const char* Bl = lds[buf] + 16384;
        #pragma unroll
        for (int s = 0; s < 2; s++) {
            const int swz = (s * 64 + lg * 16) ^ ((lr & 7) << 4);
            bf16x8 af[4], bfr[4];
            #pragma unroll
            for (int mi = 0; mi < 4; mi++)
                af[mi] = *reinterpret_cast<const bf16x8*>(Al + (wr * 64 + mi * 16 + lr) * 128 + swz);
            #pragma unroll
            for (int ni = 0; ni < 4; ni++)
                bfr[ni] = *reinterpret_cast<const bf16x8*>(Bl + (wc * 64 + ni * 16 + lr) * 128 + swz);
            #pragma unroll
            for (int mi = 0; mi < 4; mi++)
                #pragma unroll
                for (int ni = 0; ni < 4; ni++)
                    acc[mi][ni] = MFMA(af[mi], bfr[ni], acc[mi][ni]);
        }
        __syncthreads();
        buf ^= 1;
    }

    // epilogue
    #pragma unroll
    for (int mi = 0; mi < 4; mi++) {
        #pragma unroll
        for (int ni = 0; ni < 4; ni++) {
            int nn = n0 + wc * 64 + ni * 16 + lr;
            #pragma unroll
            for (int r = 0; r < 4; r++) {
                int mm = m0 + wr * 64 + mi * 16 + lg * 4 + r;
                float v = acc[mi][ni][r];
                if (MODE == 0) {
                    if (nn < 2048) {
                        Cb[(size_t)mm * NQKV + nn] = f2bf(v);
                    } else {
                        int b = mm >> 11, sIdx = mm & 2047;
                        int hd = nn - 2048;
                        vT[(((size_t)(b * HH + (hd >> 6)) * DH) + (hd & 63)) * SS + sIdx] = f2bf(v);
                    }
                } else if (MODE == 1) {
                    Cf[(size_t)mm * N + nn] = v + bias[nn] + res[(size_t)mm * N + nn];
                } else {
                    float u = v + bias[nn];
                    float gl = 0.5f * u * (1.0f + erff(u * 0.70710678118654752f));
                    Cb[(size_t)mm * N + nn] = f2bf(gl);
                }
            }
        }
    }
}

// ---------------- flash attention, swapped-QK 32x32, block-shared K/V in LDS ----
// XCD-aware block swizzle: XCD j owns heads 4j..4j+3 -> K/V (2MB) L2-resident.
__global__ __launch_bounds__(256)
void k_attn(const u16* __restrict__ qkv, const u16* __restrict__ vT,
            u16* __restrict__ out) {
    const int w = threadIdx.x >> 6, l = threadIdx.x & 63;
    const int q = l & 31, hi = l >> 5;
    const int task = (blockIdx.x & 7) * 64 + (blockIdx.x >> 3);  // 512-block bijection
    const int bh = task >> 4;                // 0..31
    const int qg = task & 15;
    const int b = bh >> 4, h = bh & 15;
    const size_t rowbase = (size_t)b * SS;
    const int q0 = (qg * 4 + w) * 32;

    __shared__ __align__(128) u16 Kl[2][32 * 64];
    __shared__ __align__(128) u16 Vl[2][32 * 64];

    const u16* kbase = qkv + rowbase * NQKV + 1024 + h * DH;
    const u16* vbase = vT + (size_t)bh * DH * SS;

    // staging: wave w owns LDS chunk w (1024B = rows w*8..w*8+7); lane l -> row
    // w*8+(l>>3), LDS slot (l&7); source col slot = (l&7)^(l>>3) (inverse swizzle).
    const int srow = w * 8 + (l >> 3);
    const int sslot = (l & 7) ^ (l >> 3);
    const u16* kg = kbase + (size_t)srow * NQKV + sslot * 8;
    const u16* vg = vbase + (size_t)(srow + 32 * (sslot >> 2)) * SS + (sslot & 3) * 8;

    // Q B-fragments: lane needs Q[q0+q][h*64 + ks*16 + hi*8 + j]
    const u16* qrow = qkv + (rowbase + q0 + q) * NQKV + h * DH + hi * 8;
    bf16x8 qf[4];
    #pragma unroll
    for (int ks = 0; ks < 4; ks++)
        qf[ks] = *reinterpret_cast<const bf16x8*>(qrow + ks * 16);

    f32x16 o0 = zero16(), o1 = zero16();     // O^T[d][q], d-tiles 0/1
    float mQ = -1e30f, lQ = 0.f;

    // prologue: stage tile 0 -> buf 0
    __builtin_amdgcn_global_load_lds(GLD_AS1(kg), GLD_AS3((u16*)Kl[0] + w * 512), 16, 0, 0);
    __builtin_amdgcn_global_load_lds(GLD_AS1(vg), GLD_AS3((u16*)Vl[0] + w * 512), 16, 0, 0);
    __syncthreads();

    int buf = 0;
    for (int kv0 = 0; kv0 < SS; kv0 += 32) {
        if (kv0 + 32 < SS) {
            __builtin_amdgcn_global_load_lds(GLD_AS1(kg + (size_t)(kv0 + 32) * NQKV),
                                             GLD_AS3((u16*)Kl[buf ^ 1] + w * 512), 16, 0, 0);
            __builtin_amdgcn_global_load_lds(GLD_AS1(vg + (kv0 + 32)),
                                             GLD_AS3((u16*)Vl[buf ^ 1] + w * 512), 16, 0, 0);
        }
        const u16* Kb = Kl[buf];
        const u16* Vb = Vl[buf];
        const int qsw = (q & 7) << 3;

        f32x16 st = zero16();
        #pragma unroll
        for (int ks = 0; ks < 4; ks++) {
            bf16x8 kf = *reinterpret_cast<const bf16x8*>(Kb + q * 64 + ((ks * 16 + hi * 8) ^ qsw));
            st = MFMA32(kf, qf[ks], st);
        }

        f32x16 sc = st * 0.125f;
        float tm = sc[0];
        #pragma unroll
        for (int i = 1; i < 16; i++) tm = fmaxf(tm, sc[i]);
        tm = fmaxf(tm, __shfl_xor(tm, 32));

        // defer-max (T13)
        if (!__all(tm - mQ <= 8.f)) {
            float mn = fmaxf(mQ, tm);
            float scale = __expf(mQ - mn);
            lQ *= scale;
            o0 *= scale;
            o1 *= scale;
            mQ = mn;
        }

        f32x16 p;
        #pragma unroll
        for (int i = 0; i < 16; i++) p[i] = __expf(sc[i] - mQ);
        float ts = p[0];
        #pragma unroll
        for (int i = 1; i < 16; i++) ts += p[i];
        ts += __shfl_xor(ts, 32);
        lQ += ts;

        // pack P to bf16 words
        union W { unsigned int u; __bf16 h[2]; };
        W pw[8];
        #pragma unroll
        for (int m = 0; m < 8; m++) {
            pw[m].h[0] = (__bf16)p[2 * m];
            pw[m].h[1] = (__bf16)p[2 * m + 1];
        }

        // build P B-fragments B[k=kv][n=q] for kk=0,1
        bf16x8 pf[2];
        #pragma unroll
        for (int kk = 0; kk < 2; kk++) {
            unsigned int a0 = pw[4 * kk + 0].u, a1 = pw[4 * kk + 1].u;
            unsigned int b0 = pw[4 * kk + 2].u, b1 = pw[4 * kk + 3].u;
            unsigned int own0 = hi ? b0 : a0, own1 = hi ? b1 : a1;
            unsigned int snd0 = hi ? a0 : b0, snd1 = hi ? a1 : b1;
            unsigned int r0 = __shfl_xor(snd0, 32), r1 = __shfl_xor(snd1, 32);
            union F { unsigned int u[4]; bf16x8 v; } f;
            f.u[0] = hi ? r0 : own0;
            f.u[1] = hi ? r1 : own1;
            f.u[2] = hi ? own0 : r0;
            f.u[3] = hi ? own1 : r1;
            pf[kk] = f.v;
        }

        // PV from LDS V tile: o0 rows d=q (slots 0-3), o1 rows d=q+32 (slots 4-7)
        #pragma unroll
        for (int kk = 0; kk < 2; kk++) {
            bf16x8 v0 = *reinterpret_cast<const bf16x8*>(Vb + q * 64 + ((kk * 16 + hi * 8) ^ qsw));
            bf16x8 v1 = *reinterpret_cast<const bf16x8*>(Vb + q * 64 + ((32 + kk * 16 + hi * 8) ^ qsw));
            o0 = MFMA32(v0, pf[kk], o0);
            o1 = MFMA32(v1, pf[kk], o1);
        }

        __syncthreads();
        buf ^= 1;
    }

    // epilogue: lane q; reg r -> d = dt*32 + (r&3) + 8*(r>>2) + 4*hi
    float invl = 1.0f / lQ;
    u16* orow = out + (rowbase + q0 + q) * DD + h * DH + hi * 4;
    #pragma unroll
    for (int a = 0; a < 4; a++) {
        u16x4 s0v, s1v;
        #pragma unroll
        for (int i = 0; i < 4; i++) {
            s0v[i] = f2bf(o0[4 * a + i] * invl);
            s1v[i] = f2bf(o1[4 * a + i] * invl);
        }
        *reinterpret_cast<u16x4*>(orow + 8 * a)      = s0v;
        *reinterpret_cast<u16x4*>(orow + 32 + 8 * a) = s1v;
    }
}

extern "C" void kernel_launch(void* const* d_in, const int* in_sizes, int n_in,
                              void* d_out, int out_size, void* d_ws, size_t ws_size,
                              hipStream_t stream) {
    (void)in_sizes; (void)n_in; (void)out_size; (void)ws_size;
    const float* x     = (const float*)d_in[0];
    const float* w_qkv = (const float*)d_in[1];
    const float* w_out = (const float*)d_in[2];
    const float* b_out = (const float*)d_in[3];
    const float* g1    = (const float*)d_in[4];
    const float* be1   = (const float*)d_in[5];
    const float* g2    = (const float*)d_in[6];
    const float* be2   = (const float*)d_in[7];
    const float* w_ff1 = (const float*)d_in[8];
    const float* b_ff1 = (const float*)d_in[9];
    const float* w_ff2 = (const float*)d_in[10];
    const float* b_ff2 = (const float*)d_in[11];

    char* ws = (char*)d_ws;
    u16*   W  = (u16*)(ws);                  //  8.39 MB  (weight^T scratch, reused)
    u16*   Hb = (u16*)(ws + 8388608);        //  8.39 MB  (LN output bf16)
    u16*   QF = (u16*)(ws + 16777216);       // 33.55 MB  (qkv, later ffn act)
    u16*   VT = (u16*)(ws + 50331648);       //  8.39 MB  (v transposed)
    u16*   AO = (u16*)(ws + 58720256);       //  8.39 MB  (attn out bf16)
    float* X1 = (float*)(ws + 67108864);     // 16.78 MB  (post-attn residual fp32)
    float* OUT = (float*)d_out;

    // LN1: x -> Hb
    k_layernorm<<<NTOK, 256, 0, stream>>>(x, g1, be1, Hb);
    // w_qkv^T
    k_transpose<<<dim3(3072 / 32, 1024 / 32), dim3(32, 8), 0, stream>>>(w_qkv, W, 1024, 3072);
    // qkv = Hb @ w_qkv   (v written transposed to VT)
    k_gemm<0><<<dim3(3072 / 128, 4096 / 128), 256, 0, stream>>>(
        Hb, W, nullptr, QF, nullptr, nullptr, VT, NTOK, NQKV, 1024);
    // attention (512 blocks, XCD-swizzled)
    k_attn<<<512, 256, 0, stream>>>(QF, VT, AO);
    // w_out^T
    k_transpose<<<dim3(1024 / 32, 1024 / 32), dim3(32, 8), 0, stream>>>(w_out, W, 1024, 1024);
    // X1 = x + AO @ w_out + b_out
    k_gemm<1><<<dim3(1024 / 128, 4096 / 128), 256, 0, stream>>>(
        AO, W, X1, nullptr, b_out, x, nullptr, NTOK, 1024, 1024);
    // LN2: X1 -> Hb
    k_layernorm<<<NTOK, 256, 0, stream>>>(X1, g2, be2, Hb);
    // w_ff1^T
    k_transpose<<<dim3(4096 / 32, 1024 / 32), dim3(32, 8), 0, stream>>>(w_ff1, W, 1024, 4096);
    // FFA = gelu(Hb @ w_ff1 + b_ff1)  (into QF region)
    k_gemm<2><<<dim3(4096 / 128, 4096 / 128), 256, 0, stream>>>(
        Hb, W, nullptr, QF, b_ff1, nullptr, nullptr, NTOK, 4096, 1024);
    // w_ff2^T
    k_transpose<<<dim3(1024 / 32, 4096 / 32), dim3(32, 8), 0, stream>>>(w_ff2, W, 4096, 1024);
    // OUT = X1 + FFA @ w_ff2 + b_ff2
    k_gemm<1><<<dim3(1024 / 128, 4096 / 128), 256, 0, stream>>>(
        QF, W, OUT, nullptr, b_ff2, X1, nullptr, NTOK, 1024, 4096);
}